// Round 3
// baseline (1007.636 us; speedup 1.0000x reference)
//
#include <hip/hip_runtime.h>
#include <stdint.h>

typedef unsigned short u16;
typedef short bf16x8 __attribute__((ext_vector_type(8)));
typedef float f32x4 __attribute__((ext_vector_type(4)));
typedef u16 u16x8 __attribute__((ext_vector_type(8)));
typedef u16 u16x4v __attribute__((ext_vector_type(4)));

#define EMBED 512
#define NBATCH 8
#define QLEN 2048
#define KLEN 4096

__device__ __forceinline__ u16 f2bf(float f) {
  uint32_t u = __builtin_bit_cast(uint32_t, f);
  u += 0x7fffu + ((u >> 16) & 1u);   // RNE
  return (u16)(u >> 16);
}
__device__ __forceinline__ float bf2f(u16 b) {
  return __builtin_bit_cast(float, (uint32_t)b << 16);
}

// async global->LDS, 16B per lane. LDS dest = wave-uniform base + lane*16 (linear).
__device__ __forceinline__ void gload_lds16(const void* g, void* lds) {
  __builtin_amdgcn_global_load_lds(
      (__attribute__((address_space(1))) void*)(uintptr_t)g,
      (__attribute__((address_space(3))) void*)(uint32_t)(uintptr_t)lds,
      16, 0, 0);
}

// one kernel converts all six fp32 inputs into the contiguous bf16 region at
// the start of ws (layout: xb | yb | Wqb | Wkb | Wvb | Wob)
__global__ __launch_bounds__(256) void cvt_all_kernel(
    const float* __restrict__ x, const float* __restrict__ y,
    const float* __restrict__ wq, const float* __restrict__ wk,
    const float* __restrict__ wv, const float* __restrict__ wo,
    u16* __restrict__ dst) {
  const int64_t B0 = 2097152;        // nx/4
  const int64_t B1 = B0 + 4194304;   // + ny/4
  const int64_t B2 = B1 + 65536;
  const int64_t B3 = B2 + 65536;
  const int64_t B4 = B3 + 65536;
  int64_t i = (int64_t)blockIdx.x * 256 + threadIdx.x;  // float4 units
  const float* src; int64_t off;
  if (i < B0)      { src = x;  off = 0;  }
  else if (i < B1) { src = y;  off = B0; }
  else if (i < B2) { src = wq; off = B1; }
  else if (i < B3) { src = wk; off = B2; }
  else if (i < B4) { src = wv; off = B3; }
  else             { src = wo; off = B4; }
  float4 f = ((const float4*)src)[i - off];
  u16x4v o = { f2bf(f.x), f2bf(f.y), f2bf(f.z), f2bf(f.w) };
  ((u16x4v*)dst)[i] = o;
}

// ---------------------------------------------------------------------------
// Generic C = A * B^T   (A: MxK bf16 row-major, B: NxK bf16 row-major)
// 128x128 tile, BK=64, 4 waves (each 64x64), mfma_f32_16x16x32_bf16.
// ---------------------------------------------------------------------------
constexpr int EPI_BF16 = 0;        // C bf16 [M][N]
constexpr int EPI_BF16_SCALE = 1;  // C bf16 = acc*scale
constexpr int EPI_BF16_TRANS = 2;  // Vt[nb][d=col][k=row%4096] bf16
constexpr int EPI_F32_RESID = 3;   // C f32 = acc + xres + bias[col]

template <int MODE>
__global__ __launch_bounds__(256, 2) void gemm_bt(
    const u16* __restrict__ A, const u16* __restrict__ B, void* __restrict__ Cv,
    int M, int N, int K,
    int64_t aBatch, int64_t bBatch, int64_t cBatch,
    float scale, const float* __restrict__ xres, const float* __restrict__ bias,
    u16* __restrict__ Vt) {
  __shared__ __align__(16) u16 As[128 * 64];
  __shared__ __align__(16) u16 Bs[128 * 64];

  const int tid = threadIdx.x;
  const int wave = tid >> 6;
  const int lane = tid & 63;
  const int bz = blockIdx.z;
  const int row0 = blockIdx.x * 128;
  const int col0 = blockIdx.y * 128;
  const u16* Ab = A + (int64_t)bz * aBatch;
  const u16* Bb = B + (int64_t)bz * bBatch;

  const int srow = wave * 32 + (lane >> 3);
  const int scol = (lane & 7) * 8;
  const u16* aSrc = Ab + (int64_t)(row0 + srow) * K + scol;
  const u16* bSrc = Bb + (int64_t)(col0 + srow) * K + scol;

  const int wm = (wave >> 1) * 64;
  const int wn = (wave & 1) * 64;
  const int fr = lane & 15;
  const int fq = lane >> 4;

  f32x4 acc[4][4];
#pragma unroll
  for (int mi = 0; mi < 4; ++mi)
#pragma unroll
    for (int ni = 0; ni < 4; ++ni) acc[mi][ni] = 0.0f;

  const int nkt = K >> 6;
  for (int kt = 0; kt < nkt; ++kt) {
    __syncthreads();
    const u16* aS = aSrc + kt * 64;
    const u16* bS = bSrc + kt * 64;
#pragma unroll
    for (int i = 0; i < 4; ++i) {
      gload_lds16(aS + (int64_t)(i * 8) * K, &As[(wave * 32 + i * 8) * 64]);
      gload_lds16(bS + (int64_t)(i * 8) * K, &Bs[(wave * 32 + i * 8) * 64]);
    }
    __syncthreads();
#pragma unroll
    for (int ks = 0; ks < 2; ++ks) {
      bf16x8 af[4], bfr[4];
#pragma unroll
      for (int mi = 0; mi < 4; ++mi)
        af[mi] = *(const bf16x8*)&As[(wm + mi * 16 + fr) * 64 + ks * 32 + fq * 8];
#pragma unroll
      for (int ni = 0; ni < 4; ++ni)
        bfr[ni] = *(const bf16x8*)&Bs[(wn + ni * 16 + fr) * 64 + ks * 32 + fq * 8];
#pragma unroll
      for (int mi = 0; mi < 4; ++mi)
#pragma unroll
        for (int ni = 0; ni < 4; ++ni)
          acc[mi][ni] = __builtin_amdgcn_mfma_f32_16x16x32_bf16(af[mi], bfr[ni],
                                                                acc[mi][ni], 0, 0, 0);
    }
  }

  // C/D layout: col = lane&15, row = (lane>>4)*4 + reg  [m89-verified]
  if constexpr (MODE == EPI_BF16 || MODE == EPI_BF16_SCALE) {
    u16* C = (u16*)Cv + (int64_t)bz * cBatch;
#pragma unroll
    for (int mi = 0; mi < 4; ++mi) {
      const int rowb = row0 + wm + mi * 16 + fq * 4;
#pragma unroll
      for (int ni = 0; ni < 4; ++ni) {
        const int col = col0 + wn + ni * 16 + fr;
#pragma unroll
        for (int r = 0; r < 4; ++r) {
          float v = acc[mi][ni][r];
          if constexpr (MODE == EPI_BF16_SCALE) v *= scale;
          C[(int64_t)(rowb + r) * N + col] = f2bf(v);
        }
      }
    }
  } else if constexpr (MODE == EPI_BF16_TRANS) {
#pragma unroll
    for (int mi = 0; mi < 4; ++mi) {
      const int rowb = row0 + wm + mi * 16 + fq * 4;
      const int nb = rowb >> 12;
      const int kk = rowb & 4095;
#pragma unroll
      for (int ni = 0; ni < 4; ++ni) {
        const int col = col0 + wn + ni * 16 + fr;
        u16x4v o = { f2bf(acc[mi][ni][0]), f2bf(acc[mi][ni][1]),
                     f2bf(acc[mi][ni][2]), f2bf(acc[mi][ni][3]) };
        *(u16x4v*)&Vt[((int64_t)nb * EMBED + col) * KLEN + kk] = o;
      }
    }
  } else {  // EPI_F32_RESID
    float* C = (float*)Cv;
#pragma unroll
    for (int mi = 0; mi < 4; ++mi) {
      const int rowb = row0 + wm + mi * 16 + fq * 4;
#pragma unroll
      for (int ni = 0; ni < 4; ++ni) {
        const int col = col0 + wn + ni * 16 + fr;
        const float bv = bias[col];
#pragma unroll
        for (int r = 0; r < 4; ++r) {
          const int64_t idx = (int64_t)(rowb + r) * N + col;
          C[idx] = acc[mi][ni][r] + xres[idx] + bv;
        }
      }
    }
  }
}

// ---------------------------------------------------------------------------
// Fused flash attention — in-block split-K for occupancy.
//
// R2 post-mortem: __launch_bounds__(512,2) made the compiler budget for
// 4 waves/SIMD -> VGPR capped at 128, but live state is ~228 regs
// (o[32]=128 + q[16]=64) -> scratch spills: FETCH_SIZE 41MB -> 970MB,
// attn 893us. The split-K structure itself was fine (occupancy hit 23%).
// Fix: __launch_bounds__(512,1). The 512-thread workgroup (8 waves on 4
// SIMDs) itself forces VGPR<=256 so 2 waves/SIMD still co-reside; compiler
// returns to ~228 VGPR, zero spill, and the latency-overlap experiment
// actually runs.
//
// Structure: two independent 4-wave groups. Group g handles key tiles
// [g*64, g*64+64) with its own K double-buffer / P buffer / alpha array.
// 2 waves/SIMD -> one group's stalls (shuffle-reduce chains, L3 latency,
// barriers) are covered by the other group's MFMA/VALU. Final merge of the
// two online-softmax halves in LDS (f32, reusing the dead K buffers):
//   M = max(m0,m1); f_g = exp(m_g-M) / (l0*e^{m0-M}+l1*e^{m1-M});
//   O = f0*o0 + f1*o1.
// LDS: 4x32KB (K) + 2x4KB (P) + stats = ~140.8KB.
// ---------------------------------------------------------------------------
__global__ __launch_bounds__(512, 1) void attn_kernel(
    const u16* __restrict__ Qm, const u16* __restrict__ Km,
    const u16* __restrict__ Vt, u16* __restrict__ O) {
  __shared__ __align__(16) u16 Ks[2][2][32 * 512];  // [group][slot] 4 x 32KB
  __shared__ __align__(16) u16 Ps[2][64 * 32];      // [group] 2 x 4KB
  __shared__ __align__(16) float Als[2][64];        // per-group alpha
  __shared__ float Mls[2][64], Lls[2][64];          // merge stats

  const int tid = threadIdx.x;
  const int w = tid >> 6;       // 0..7
  const int g = w >> 2;         // key-half group
  const int wg = w & 3;         // role within group
  const int lane = tid & 63;
  const int fr = lane & 15, fq = lane >> 4;
  const int s7 = fr & 7;
  const int nb = blockIdx.x & 7;   // batch -> XCD (round-robin dispatch)
  const int qt = blockIdx.x >> 3;

  // Q fragments: 16 q rows per wave (A-frag: lane fr = row, fq*8 = k-chunk).
  // Both groups load the same Q rows (same q tile, different keys).
  bf16x8 q[16];
  {
    const u16* Qb = Qm + ((int64_t)nb * QLEN + qt * 64 + wg * 16 + fr) * EMBED + fq * 8;
#pragma unroll
    for (int kc = 0; kc < 16; ++kc) q[kc] = *(const bf16x8*)&Qb[kc * 32];
  }

  f32x4 o[32];  // o[mi*8+ni]: q row mi*16+fq*4+r, d col wg*128+ni*16+fr
#pragma unroll
  for (int i = 0; i < 32; ++i) o[i] = 0.0f;
  f32x4 mrun, lrun;
#pragma unroll
  for (int r = 0; r < 4; ++r) { mrun[r] = -1e30f; lrun[r] = 0.0f; }

  const u16* Kb = Km + (int64_t)nb * KLEN * EMBED;
  const u16* VbW = Vt + (int64_t)nb * (int64_t)EMBED * KLEN + (int64_t)(wg * 128) * KLEN;

  const int NT = KLEN / 32 / 2;  // 64 tiles per group
  const int t0 = g * NT;         // group's first tile

  // prologue: stage group's K tile 0 (swizzle: src chunk = lane ^ (row&7))
  {
    const u16* src = Kb + ((int64_t)t0 * 32 + wg * 8) * EMBED;
#pragma unroll
    for (int i = 0; i < 8; ++i)
      gload_lds16(src + (int64_t)i * EMBED + (lane ^ i) * 8,
                  &Ks[g][0][(wg * 8 + i) * 512]);
  }
  __syncthreads();

  for (int t = 0; t < NT; ++t) {
    const int cur = t & 1;
    const int tt = t0 + t;
    // prefetch K[tt+1] into other slot (drained by iter-end __syncthreads)
    if (t + 1 < NT) {
      const u16* src = Kb + ((int64_t)(tt + 1) * 32 + wg * 8) * EMBED;
#pragma unroll
      for (int i = 0; i < 8; ++i)
        gload_lds16(src + (int64_t)i * EMBED + (lane ^ i) * 8,
                    &Ks[g][cur ^ 1][(wg * 8 + i) * 512]);
    }
    // V fragments for this tile: global -> regs, issued early (T14)
    bf16x8 vf[8];
#pragma unroll
    for (int ni = 0; ni < 8; ++ni)
      vf[ni] = *(const bf16x8*)&VbW[(int64_t)(ni * 16 + fr) * KLEN + tt * 32 + fq * 8];

    // S = Q K^T  (16 q rows x 32 keys per wave)
    const u16* Kc = Ks[g][cur];
    f32x4 s[2];
    s[0] = 0.0f; s[1] = 0.0f;
#pragma unroll
    for (int kc = 0; kc < 16; ++kc) {
#pragma unroll
      for (int ni = 0; ni < 2; ++ni) {
        bf16x8 b = *(const bf16x8*)&Kc[(ni * 16 + fr) * 512 + (((kc * 4 + fq) ^ s7) * 8)];
        s[ni] = __builtin_amdgcn_mfma_f32_16x16x32_bf16(q[kc], b, s[ni], 0, 0, 0);
      }
    }

    // online softmax with defer-max (T13, THR=8)
    f32x4 mt;
#pragma unroll
    for (int r = 0; r < 4; ++r) mt[r] = fmaxf(s[0][r], s[1][r]);
#pragma unroll
    for (int off = 1; off <= 8; off <<= 1)
#pragma unroll
      for (int r = 0; r < 4; ++r) mt[r] = fmaxf(mt[r], __shfl_xor(mt[r], off));
    int ok = 1;
#pragma unroll
    for (int r = 0; r < 4; ++r) ok &= (mt[r] <= mrun[r] + 8.0f);
    f32x4 alpha;
    if (__all(ok)) {
#pragma unroll
      for (int r = 0; r < 4; ++r) alpha[r] = 1.0f;
    } else {
#pragma unroll
      for (int r = 0; r < 4; ++r) {
        float mn = fmaxf(mrun[r], mt[r]);
        alpha[r] = __expf(mrun[r] - mn);
        lrun[r] *= alpha[r];
        mrun[r] = mn;
      }
    }
    float p[2][4];
    f32x4 rs;
#pragma unroll
    for (int r = 0; r < 4; ++r) rs[r] = 0.0f;
#pragma unroll
    for (int ni = 0; ni < 2; ++ni)
#pragma unroll
      for (int r = 0; r < 4; ++r) {
        p[ni][r] = __expf(s[ni][r] - mrun[r]);
        rs[r] += p[ni][r];
      }
#pragma unroll
    for (int off = 1; off <= 8; off <<= 1)
#pragma unroll
      for (int r = 0; r < 4; ++r) rs[r] += __shfl_xor(rs[r], off);
#pragma unroll
    for (int r = 0; r < 4; ++r) lrun[r] += rs[r];

    // P -> LDS. Swizzle: phys_chunk = logical ^ (row&3) ^ ((row>>2)&3);
    // write row = wg*16+fq*4+r -> row&3=r, (row>>2)&3=fq.
#pragma unroll
    for (int ni = 0; ni < 2; ++ni)
#pragma unroll
      for (int r = 0; r < 4; ++r)
        Ps[g][(wg * 16 + fq * 4 + r) * 32 + (((ni * 2 + (fr >> 3)) ^ r ^ fq) * 8) + (fr & 7)]
            = f2bf(p[ni][r]);
    if (fr == 0) {
#pragma unroll
      for (int r = 0; r < 4; ++r) Als[g][wg * 16 + fq * 4 + r] = alpha[r];
    }

    // P/alpha visible to all waves WITHOUT draining vmcnt (prefetch in flight)
    asm volatile("s_waitcnt lgkmcnt(0)" ::: "memory");
    __builtin_amdgcn_sched_barrier(0);
    __builtin_amdgcn_s_barrier();
    __builtin_amdgcn_sched_barrier(0);

    // rescale o by cross-wave alphas (skipped when all alpha == 1)
    f32x4 ra[4];
#pragma unroll
    for (int mi = 0; mi < 4; ++mi) ra[mi] = *(const f32x4*)&Als[g][mi * 16 + fq * 4];
    int nz = 0;
#pragma unroll
    for (int mi = 0; mi < 4; ++mi)
#pragma unroll
      for (int r = 0; r < 4; ++r) nz |= (ra[mi][r] != 1.0f);
    if (__any(nz)) {
#pragma unroll
      for (int mi = 0; mi < 4; ++mi)
#pragma unroll
        for (int ni = 0; ni < 8; ++ni)
#pragma unroll
          for (int r = 0; r < 4; ++r) o[mi * 8 + ni][r] *= ra[mi][r];
    }

    // PV: A-frag row = mi*16+fr -> row&3=fr&3, (row>>2)&3=(fr>>2)&3
    bf16x8 ap[4];
#pragma unroll
    for (int mi = 0; mi < 4; ++mi)
      ap[mi] = *(const bf16x8*)&Ps[g][(mi * 16 + fr) * 32 +
                                      ((fq ^ (fr & 3) ^ ((fr >> 2) & 3)) * 8)];
#pragma unroll
    for (int mi = 0; mi < 4; ++mi)
#pragma unroll
      for (int ni = 0; ni < 8; ++ni)
        o[mi * 8 + ni] = __builtin_amdgcn_mfma_f32_16x16x32_bf16(ap[mi], vf[ni],
                                                                 o[mi * 8 + ni], 0, 0, 0);

    __syncthreads();  // single vmcnt(0) drain: K prefetch landed; Ps/Ks safe
  }

  // ---- merge the two key-halves ----
  if (fr == 0) {
#pragma unroll
    for (int r = 0; r < 4; ++r) {
      Mls[g][wg * 16 + fq * 4 + r] = mrun[r];
      Lls[g][wg * 16 + fq * 4 + r] = lrun[r];
    }
  }
  __syncthreads();

  // per-row merge factors (each wave covers all 64 rows via mi)
  f32x4 fac[4];  // factor for this thread's group, rows mi*16+fq*4+r
#pragma unroll
  for (int mi = 0; mi < 4; ++mi) {
#pragma unroll
    for (int r = 0; r < 4; ++r) {
      const int row = mi * 16 + fq * 4 + r;
      const float m0 = Mls[0][row], m1 = Mls[1][row];
      const float M = fmaxf(m0, m1);
      const float e0 = __expf(m0 - M), e1 = __expf(m1 - M);
      const float L = Lls[0][row] * e0 + Lls[1][row] * e1;
      const float inv = 1.0f / L;
      fac[mi][r] = (g == 0 ? e0 : e1) * inv;
    }
  }

  // group 0 deposits scaled partial (f32) into the dead K buffers (128KB)
  float* Mb = (float*)&Ks[0][0][0];  // [64][512] f32 = 128KB <= 131072B
  if (g == 0) {
#pragma unroll
    for (int mi = 0; mi < 4; ++mi)
#pragma unroll
      for (int ni = 0; ni < 8; ++ni)
#pragma unroll
        for (int r = 0; r < 4; ++r)
          Mb[(mi * 16 + fq * 4 + r) * 512 + wg * 128 + ni * 16 + fr] =
              o[mi * 8 + ni][r] * fac[mi][r];
  }
  __syncthreads();

  // group 1 adds its scaled partial and stores the final O tile
  if (g == 1) {
    u16* Ob = O + ((int64_t)nb * QLEN + qt * 64) * EMBED + wg * 128;
#pragma unroll
    for (int mi = 0; mi < 4; ++mi)
#pragma unroll
      for (int ni = 0; ni < 8; ++ni)
#pragma unroll
        for (int r = 0; r < 4; ++r) {
          const int row = mi * 16 + fq * 4 + r;
          const int col = ni * 16 + fr;
          const float v = Mb[row * 512 + wg * 128 + col] +
                          o[mi * 8 + ni][r] * fac[mi][r];
          Ob[(int64_t)row * EMBED + col] = f2bf(v);
        }
  }
}

extern "C" void kernel_launch(void* const* d_in, const int* in_sizes, int n_in,
                              void* d_out, int out_size, void* d_ws, size_t ws_size,
                              hipStream_t stream) {
  const float* x  = (const float*)d_in[0];
  const float* y  = (const float*)d_in[1];
  const float* Wq = (const float*)d_in[2];
  const float* Wk = (const float*)d_in[3];
  const float* Wv = (const float*)d_in[4];
  const float* Wo = (const float*)d_in[5];
  const float* bo = (const float*)d_in[6];
  float* out = (float*)d_out;

  const int64_t nx = (int64_t)NBATCH * QLEN * EMBED;  // 8,388,608
  const int64_t ny = (int64_t)NBATCH * KLEN * EMBED;  // 16,777,216
  const int64_t nw = (int64_t)EMBED * EMBED;          // 262,144

  // ws layout (bf16): xb | yb | Wqb | Wkb | Wvb | Wob | Qm | Km | Vt  (~136MB)
  u16* w   = (u16*)d_ws;
  u16* xb  = w;            // dead after Q projection
  u16* O   = w; w += nx;   // attn output overlays xb
  u16* yb  = w; w += ny;
  u16* Wqb = w; w += nw;
  u16* Wkb = w; w += nw;
  u16* Wvb = w; w += nw;
  u16* Wob = w; w += nw;
  u16* Qm  = w; w += nx;
  u16* Km  = w; w += ny;
  u16* Vt  = w; w += ny;   // [8][512][4096]

  // one fused fp32->bf16 conversion over the contiguous region
  cvt_all_kernel<<<25600, 256, 0, stream>>>(x, y, Wq, Wk, Wv, Wo, xb);

  // Qm = (x@Wq^T) * 1/sqrt(512)
  const float scal = 0.04419417382415922f;
  gemm_bt<EPI_BF16_SCALE><<<dim3(128, 4, 1), 256, 0, stream>>>(
      xb, Wqb, Qm, 16384, EMBED, EMBED, 0, 0, 0, scal, nullptr, nullptr, nullptr);
  gemm_bt<EPI_BF16><<<dim3(256, 4, 1), 256, 0, stream>>>(
      yb, Wkb, Km, 32768, EMBED, EMBED, 0, 0, 0, 1.f, nullptr, nullptr, nullptr);
  gemm_bt<EPI_BF16_TRANS><<<dim3(256, 4, 1), 256, 0, stream>>>(
      yb, Wvb, nullptr, 32768, EMBED, EMBED, 0, 0, 0, 1.f, nullptr, nullptr, Vt);

  // fused attention (writes O over the dead xb slot)
  attn_kernel<<<NBATCH * 32, 512, 0, stream>>>(Qm, Km, Vt, O);

  // out = x + O @ Wo^T + bo   (fp32 epilogue)
  gemm_bt<EPI_F32_RESID><<<dim3(128, 4, 1), 256, 0, stream>>>(
      O, Wob, out, 16384, EMBED, EMBED, 0, 0, 0, 1.f, x, bo, nullptr);
}

// Round 4
// 484.682 us; speedup vs baseline: 2.0790x; 2.0790x over previous
//
#include <hip/hip_runtime.h>
#include <stdint.h>

typedef unsigned short u16;
typedef short bf16x8 __attribute__((ext_vector_type(8)));
typedef float f32x4 __attribute__((ext_vector_type(4)));
typedef u16 u16x8 __attribute__((ext_vector_type(8)));
typedef u16 u16x4v __attribute__((ext_vector_type(4)));

#define EMBED 512
#define NBATCH 8
#define QLEN 2048
#define KLEN 4096

__device__ __forceinline__ u16 f2bf(float f) {
  uint32_t u = __builtin_bit_cast(uint32_t, f);
  u += 0x7fffu + ((u >> 16) & 1u);   // RNE
  return (u16)(u >> 16);
}
__device__ __forceinline__ float bf2f(u16 b) {
  return __builtin_bit_cast(float, (uint32_t)b << 16);
}

// async global->LDS, 16B per lane. LDS dest = wave-uniform base + lane*16 (linear).
__device__ __forceinline__ void gload_lds16(const void* g, void* lds) {
  __builtin_amdgcn_global_load_lds(
      (__attribute__((address_space(1))) void*)(uintptr_t)g,
      (__attribute__((address_space(3))) void*)(uint32_t)(uintptr_t)lds,
      16, 0, 0);
}

// one kernel converts all six fp32 inputs into the contiguous bf16 region at
// the start of ws (layout: xb | yb | Wqb | Wkb | Wvb | Wob)
__global__ __launch_bounds__(256) void cvt_all_kernel(
    const float* __restrict__ x, const float* __restrict__ y,
    const float* __restrict__ wq, const float* __restrict__ wk,
    const float* __restrict__ wv, const float* __restrict__ wo,
    u16* __restrict__ dst) {
  const int64_t B0 = 2097152;        // nx/4
  const int64_t B1 = B0 + 4194304;   // + ny/4
  const int64_t B2 = B1 + 65536;
  const int64_t B3 = B2 + 65536;
  const int64_t B4 = B3 + 65536;
  int64_t i = (int64_t)blockIdx.x * 256 + threadIdx.x;  // float4 units
  const float* src; int64_t off;
  if (i < B0)      { src = x;  off = 0;  }
  else if (i < B1) { src = y;  off = B0; }
  else if (i < B2) { src = wq; off = B1; }
  else if (i < B3) { src = wk; off = B2; }
  else if (i < B4) { src = wv; off = B3; }
  else             { src = wo; off = B4; }
  float4 f = ((const float4*)src)[i - off];
  u16x4v o = { f2bf(f.x), f2bf(f.y), f2bf(f.z), f2bf(f.w) };
  ((u16x4v*)dst)[i] = o;
}

// ---------------------------------------------------------------------------
// Generic C = A * B^T   (A: MxK bf16 row-major, B: NxK bf16 row-major)
// 128x128 tile, BK=64, 4 waves (each 64x64), mfma_f32_16x16x32_bf16.
// ---------------------------------------------------------------------------
constexpr int EPI_BF16 = 0;        // C bf16 [M][N]
constexpr int EPI_BF16_SCALE = 1;  // C bf16 = acc*scale
constexpr int EPI_BF16_TRANS = 2;  // Vt[nb][d=col][k=row%4096] bf16
constexpr int EPI_F32_RESID = 3;   // C f32 = acc + xres + bias[col]

template <int MODE>
__global__ __launch_bounds__(256, 2) void gemm_bt(
    const u16* __restrict__ A, const u16* __restrict__ B, void* __restrict__ Cv,
    int M, int N, int K,
    int64_t aBatch, int64_t bBatch, int64_t cBatch,
    float scale, const float* __restrict__ xres, const float* __restrict__ bias,
    u16* __restrict__ Vt) {
  __shared__ __align__(16) u16 As[128 * 64];
  __shared__ __align__(16) u16 Bs[128 * 64];

  const int tid = threadIdx.x;
  const int wave = tid >> 6;
  const int lane = tid & 63;
  const int bz = blockIdx.z;
  const int row0 = blockIdx.x * 128;
  const int col0 = blockIdx.y * 128;
  const u16* Ab = A + (int64_t)bz * aBatch;
  const u16* Bb = B + (int64_t)bz * bBatch;

  const int srow = wave * 32 + (lane >> 3);
  const int scol = (lane & 7) * 8;
  const u16* aSrc = Ab + (int64_t)(row0 + srow) * K + scol;
  const u16* bSrc = Bb + (int64_t)(col0 + srow) * K + scol;

  const int wm = (wave >> 1) * 64;
  const int wn = (wave & 1) * 64;
  const int fr = lane & 15;
  const int fq = lane >> 4;

  f32x4 acc[4][4];
#pragma unroll
  for (int mi = 0; mi < 4; ++mi)
#pragma unroll
    for (int ni = 0; ni < 4; ++ni) acc[mi][ni] = 0.0f;

  const int nkt = K >> 6;
  for (int kt = 0; kt < nkt; ++kt) {
    __syncthreads();
    const u16* aS = aSrc + kt * 64;
    const u16* bS = bSrc + kt * 64;
#pragma unroll
    for (int i = 0; i < 4; ++i) {
      gload_lds16(aS + (int64_t)(i * 8) * K, &As[(wave * 32 + i * 8) * 64]);
      gload_lds16(bS + (int64_t)(i * 8) * K, &Bs[(wave * 32 + i * 8) * 64]);
    }
    __syncthreads();
#pragma unroll
    for (int ks = 0; ks < 2; ++ks) {
      bf16x8 af[4], bfr[4];
#pragma unroll
      for (int mi = 0; mi < 4; ++mi)
        af[mi] = *(const bf16x8*)&As[(wm + mi * 16 + fr) * 64 + ks * 32 + fq * 8];
#pragma unroll
      for (int ni = 0; ni < 4; ++ni)
        bfr[ni] = *(const bf16x8*)&Bs[(wn + ni * 16 + fr) * 64 + ks * 32 + fq * 8];
#pragma unroll
      for (int mi = 0; mi < 4; ++mi)
#pragma unroll
        for (int ni = 0; ni < 4; ++ni)
          acc[mi][ni] = __builtin_amdgcn_mfma_f32_16x16x32_bf16(af[mi], bfr[ni],
                                                                acc[mi][ni], 0, 0, 0);
    }
  }

  // C/D layout: col = lane&15, row = (lane>>4)*4 + reg  [m89-verified]
  if constexpr (MODE == EPI_BF16 || MODE == EPI_BF16_SCALE) {
    u16* C = (u16*)Cv + (int64_t)bz * cBatch;
#pragma unroll
    for (int mi = 0; mi < 4; ++mi) {
      const int rowb = row0 + wm + mi * 16 + fq * 4;
#pragma unroll
      for (int ni = 0; ni < 4; ++ni) {
        const int col = col0 + wn + ni * 16 + fr;
#pragma unroll
        for (int r = 0; r < 4; ++r) {
          float v = acc[mi][ni][r];
          if constexpr (MODE == EPI_BF16_SCALE) v *= scale;
          C[(int64_t)(rowb + r) * N + col] = f2bf(v);
        }
      }
    }
  } else if constexpr (MODE == EPI_BF16_TRANS) {
#pragma unroll
    for (int mi = 0; mi < 4; ++mi) {
      const int rowb = row0 + wm + mi * 16 + fq * 4;
      const int nb = rowb >> 12;
      const int kk = rowb & 4095;
#pragma unroll
      for (int ni = 0; ni < 4; ++ni) {
        const int col = col0 + wn + ni * 16 + fr;
        u16x4v o = { f2bf(acc[mi][ni][0]), f2bf(acc[mi][ni][1]),
                     f2bf(acc[mi][ni][2]), f2bf(acc[mi][ni][3]) };
        *(u16x4v*)&Vt[((int64_t)nb * EMBED + col) * KLEN + kk] = o;
      }
    }
  } else {  // EPI_F32_RESID
    float* C = (float*)Cv;
#pragma unroll
    for (int mi = 0; mi < 4; ++mi) {
      const int rowb = row0 + wm + mi * 16 + fq * 4;
#pragma unroll
      for (int ni = 0; ni < 4; ++ni) {
        const int col = col0 + wn + ni * 16 + fr;
        const float bv = bias[col];
#pragma unroll
        for (int r = 0; r < 4; ++r) {
          const int64_t idx = (int64_t)(rowb + r) * N + col;
          C[idx] = acc[mi][ni][r] + xres[idx] + bv;
        }
      }
    }
  }
}

// ---------------------------------------------------------------------------
// Fused flash attention — GLOBAL 2-way split-K for occupancy.
//
// R3 post-mortem: 512-thread workgroups get a 128-VGPR cap on this toolchain
// regardless of the second __launch_bounds__ arg (observed twice) -> spills.
// Abandoned. Instead: keep the known-good 256-thread/228-VGPR/70KB-LDS block
// (R1 pipeline) and double resident waves via grid: dim3(256, 2), where
// blockIdx.y = key half. Two blocks co-reside per CU (2x228=456<=512 VGPR,
// 2x70KB=140KB<=160KB LDS) -> 2 waves/SIMD; one block's stalls (shuffle
// chains, L3 latency, barrier drains) overlap the other's MFMA/VALU.
//
// Each block writes an UNNORMALIZED partial O (no 1/l) + per-row (m,l):
//   half 0 -> f32 into the dead yb region (exact 33.55MB fit)
//   half 1 -> bf16 into the O region (merged in place later)
//   stats  -> dead Wqb region
// merge_kernel: O = (P0*w0 + P1*w1) / (l0*w0 + l1*w1), w_g = exp(m_g - M).
// ---------------------------------------------------------------------------
__global__ __launch_bounds__(256, 1) void attn_kernel(
    const u16* __restrict__ Qm, const u16* __restrict__ Km,
    const u16* __restrict__ Vt, u16* __restrict__ P1,
    float* __restrict__ P0, float* __restrict__ Ms, float* __restrict__ Ls) {
  __shared__ __align__(16) u16 Ks[2][32 * 512];  // 2 x 32KB
  __shared__ __align__(16) u16 Ps[64 * 32];      // 4KB, chunk-swizzled
  __shared__ __align__(16) float Als[64];        // per-q-row alpha

  const int tid = threadIdx.x;
  const int w = tid >> 6;
  const int lane = tid & 63;
  const int fr = lane & 15, fq = lane >> 4;
  const int s7 = fr & 7;
  const int nb = blockIdx.x & 7;   // batch -> XCD (round-robin dispatch)
  const int qt = blockIdx.x >> 3;
  const int g = blockIdx.y;        // key half: tiles [g*64, g*64+64)

  // Q fragments: wave w's 16 q rows (A-frag: lane fr = row, fq*8 = k-chunk)
  bf16x8 q[16];
  {
    const u16* Qb = Qm + ((int64_t)nb * QLEN + qt * 64 + w * 16 + fr) * EMBED + fq * 8;
#pragma unroll
    for (int kc = 0; kc < 16; ++kc) q[kc] = *(const bf16x8*)&Qb[kc * 32];
  }

  f32x4 o[32];  // o[mi*8+ni]: q row mi*16+fq*4+r, d col w*128+ni*16+fr
#pragma unroll
  for (int i = 0; i < 32; ++i) o[i] = 0.0f;
  f32x4 mrun, lrun;
#pragma unroll
  for (int r = 0; r < 4; ++r) { mrun[r] = -1e30f; lrun[r] = 0.0f; }

  const u16* Kb = Km + (int64_t)nb * KLEN * EMBED;
  const u16* VbW = Vt + (int64_t)nb * (int64_t)EMBED * KLEN + (int64_t)(w * 128) * KLEN;

  const int NT = 64;        // tiles per half
  const int t0 = g * NT;    // this half's first tile

  // prologue: stage K tile t0 into slot 0 (swizzle: src chunk = lane ^ (row&7))
  {
    const u16* src = Kb + ((int64_t)t0 * 32 + w * 8) * EMBED;
#pragma unroll
    for (int i = 0; i < 8; ++i)
      gload_lds16(src + (int64_t)i * EMBED + (lane ^ i) * 8, &Ks[0][(w * 8 + i) * 512]);
  }
  __syncthreads();

  for (int t = 0; t < NT; ++t) {
    const int cur = t & 1;
    const int tt = t0 + t;
    // prefetch K[tt+1] into other slot (drained by iter-end __syncthreads)
    if (t + 1 < NT) {
      const u16* src = Kb + ((int64_t)(tt + 1) * 32 + w * 8) * EMBED;
#pragma unroll
      for (int i = 0; i < 8; ++i)
        gload_lds16(src + (int64_t)i * EMBED + (lane ^ i) * 8,
                    &Ks[cur ^ 1][(w * 8 + i) * 512]);
    }
    // V fragments for this tile: global -> regs, issued early (T14)
    bf16x8 vf[8];
#pragma unroll
    for (int ni = 0; ni < 8; ++ni)
      vf[ni] = *(const bf16x8*)&VbW[(int64_t)(ni * 16 + fr) * KLEN + tt * 32 + fq * 8];

    // S = Q K^T  (16 q rows x 32 keys per wave)
    const u16* Kc = Ks[cur];
    f32x4 s[2];
    s[0] = 0.0f; s[1] = 0.0f;
#pragma unroll
    for (int kc = 0; kc < 16; ++kc) {
#pragma unroll
      for (int ni = 0; ni < 2; ++ni) {
        bf16x8 b = *(const bf16x8*)&Kc[(ni * 16 + fr) * 512 + (((kc * 4 + fq) ^ s7) * 8)];
        s[ni] = __builtin_amdgcn_mfma_f32_16x16x32_bf16(q[kc], b, s[ni], 0, 0, 0);
      }
    }

    // online softmax with defer-max (T13, THR=8)
    f32x4 mt;
#pragma unroll
    for (int r = 0; r < 4; ++r) mt[r] = fmaxf(s[0][r], s[1][r]);
#pragma unroll
    for (int off = 1; off <= 8; off <<= 1)
#pragma unroll
      for (int r = 0; r < 4; ++r) mt[r] = fmaxf(mt[r], __shfl_xor(mt[r], off));
    int ok = 1;
#pragma unroll
    for (int r = 0; r < 4; ++r) ok &= (mt[r] <= mrun[r] + 8.0f);
    f32x4 alpha;
    if (__all(ok)) {
#pragma unroll
      for (int r = 0; r < 4; ++r) alpha[r] = 1.0f;
    } else {
#pragma unroll
      for (int r = 0; r < 4; ++r) {
        float mn = fmaxf(mrun[r], mt[r]);
        alpha[r] = __expf(mrun[r] - mn);
        lrun[r] *= alpha[r];
        mrun[r] = mn;
      }
    }
    float p[2][4];
    f32x4 rs;
#pragma unroll
    for (int r = 0; r < 4; ++r) rs[r] = 0.0f;
#pragma unroll
    for (int ni = 0; ni < 2; ++ni)
#pragma unroll
      for (int r = 0; r < 4; ++r) {
        p[ni][r] = __expf(s[ni][r] - mrun[r]);
        rs[r] += p[ni][r];
      }
#pragma unroll
    for (int off = 1; off <= 8; off <<= 1)
#pragma unroll
      for (int r = 0; r < 4; ++r) rs[r] += __shfl_xor(rs[r], off);
#pragma unroll
    for (int r = 0; r < 4; ++r) lrun[r] += rs[r];

    // P -> LDS. Swizzle: phys_chunk = logical ^ (row&3) ^ ((row>>2)&3);
    // write row = w*16+fq*4+r -> row&3=r, (row>>2)&3=fq.
#pragma unroll
    for (int ni = 0; ni < 2; ++ni)
#pragma unroll
      for (int r = 0; r < 4; ++r)
        Ps[(w * 16 + fq * 4 + r) * 32 + (((ni * 2 + (fr >> 3)) ^ r ^ fq) * 8) + (fr & 7)]
            = f2bf(p[ni][r]);
    if (fr == 0) {
#pragma unroll
      for (int r = 0; r < 4; ++r) Als[w * 16 + fq * 4 + r] = alpha[r];
    }

    // P/alpha visible to all waves WITHOUT draining vmcnt (prefetch in flight)
    asm volatile("s_waitcnt lgkmcnt(0)" ::: "memory");
    __builtin_amdgcn_sched_barrier(0);
    __builtin_amdgcn_s_barrier();
    __builtin_amdgcn_sched_barrier(0);

    // rescale o by cross-wave alphas (skipped when all alpha == 1)
    f32x4 ra[4];
#pragma unroll
    for (int mi = 0; mi < 4; ++mi) ra[mi] = *(const f32x4*)&Als[mi * 16 + fq * 4];
    int nz = 0;
#pragma unroll
    for (int mi = 0; mi < 4; ++mi)
#pragma unroll
      for (int r = 0; r < 4; ++r) nz |= (ra[mi][r] != 1.0f);
    if (__any(nz)) {
#pragma unroll
      for (int mi = 0; mi < 4; ++mi)
#pragma unroll
        for (int ni = 0; ni < 8; ++ni)
#pragma unroll
          for (int r = 0; r < 4; ++r) o[mi * 8 + ni][r] *= ra[mi][r];
    }

    // PV: A-frag row = mi*16+fr -> row&3=fr&3, (row>>2)&3=(fr>>2)&3
    bf16x8 ap[4];
#pragma unroll
    for (int mi = 0; mi < 4; ++mi)
      ap[mi] = *(const bf16x8*)&Ps[(mi * 16 + fr) * 32 +
                                   ((fq ^ (fr & 3) ^ ((fr >> 2) & 3)) * 8)];
#pragma unroll
    for (int mi = 0; mi < 4; ++mi)
#pragma unroll
      for (int ni = 0; ni < 8; ++ni)
        o[mi * 8 + ni] = __builtin_amdgcn_mfma_f32_16x16x32_bf16(ap[mi], vf[ni],
                                                                 o[mi * 8 + ni], 0, 0, 0);

    __syncthreads();  // single vmcnt(0) drain: K prefetch landed; Ps/Ks safe
  }

  // ---- epilogue: per-row stats + unnormalized partial O ----
  if (fr == 0) {
#pragma unroll
    for (int r = 0; r < 4; ++r) {
      const int rowG = nb * QLEN + qt * 64 + w * 16 + fq * 4 + r;
      Ms[g * 16384 + rowG] = mrun[r];
      Ls[g * 16384 + rowG] = lrun[r];
    }
  }
  const int64_t base = ((int64_t)nb * QLEN + qt * 64) * EMBED + w * 128;
  if (g == 0) {
#pragma unroll
    for (int mi = 0; mi < 4; ++mi)
#pragma unroll
      for (int ni = 0; ni < 8; ++ni)
#pragma unroll
        for (int r = 0; r < 4; ++r)
          P0[base + (int64_t)(mi * 16 + fq * 4 + r) * EMBED + ni * 16 + fr] =
              o[mi * 8 + ni][r];
  } else {
#pragma unroll
    for (int mi = 0; mi < 4; ++mi)
#pragma unroll
      for (int ni = 0; ni < 8; ++ni)
#pragma unroll
        for (int r = 0; r < 4; ++r)
          P1[base + (int64_t)(mi * 16 + fq * 4 + r) * EMBED + ni * 16 + fr] =
              f2bf(o[mi * 8 + ni][r]);
  }
}

// Combine the two split-K halves: O = (P0*w0 + P1*w1) / (l0*w0 + l1*w1).
// P1O holds half-1's bf16 partial on input and the final O on output (same
// addresses, read-then-write within a thread).
__global__ __launch_bounds__(256) void merge_kernel(
    const float* __restrict__ P0, u16* __restrict__ P1O,
    const float* __restrict__ Ms, const float* __restrict__ Ls) {
  const int idx = blockIdx.x * 256 + threadIdx.x;  // 8-element units
  const int row = idx >> 6;                        // 64 threads per row
  const int c = (idx & 63) * 8;
  const float m0 = Ms[row], m1 = Ms[16384 + row];
  const float M = fmaxf(m0, m1);
  float w0 = __expf(m0 - M), w1 = __expf(m1 - M);
  const float inv = 1.0f / (Ls[row] * w0 + Ls[16384 + row] * w1);
  w0 *= inv; w1 *= inv;
  const int64_t off = (int64_t)row * EMBED + c;
  float4 a0 = *(const float4*)&P0[off];
  float4 a1 = *(const float4*)&P0[off + 4];
  u16x8 b = *(const u16x8*)&P1O[off];
  float av[8] = {a0.x, a0.y, a0.z, a0.w, a1.x, a1.y, a1.z, a1.w};
  u16x8 ov;
#pragma unroll
  for (int j = 0; j < 8; ++j) ov[j] = f2bf(av[j] * w0 + bf2f(b[j]) * w1);
  *(u16x8*)&P1O[off] = ov;
}

extern "C" void kernel_launch(void* const* d_in, const int* in_sizes, int n_in,
                              void* d_out, int out_size, void* d_ws, size_t ws_size,
                              hipStream_t stream) {
  const float* x  = (const float*)d_in[0];
  const float* y  = (const float*)d_in[1];
  const float* Wq = (const float*)d_in[2];
  const float* Wk = (const float*)d_in[3];
  const float* Wv = (const float*)d_in[4];
  const float* Wo = (const float*)d_in[5];
  const float* bo = (const float*)d_in[6];
  float* out = (float*)d_out;

  const int64_t nx = (int64_t)NBATCH * QLEN * EMBED;  // 8,388,608
  const int64_t ny = (int64_t)NBATCH * KLEN * EMBED;  // 16,777,216
  const int64_t nw = (int64_t)EMBED * EMBED;          // 262,144

  // ws layout (bf16): xb | yb | Wqb | Wkb | Wvb | Wob | Qm | Km | Vt  (~136MB)
  u16* w   = (u16*)d_ws;
  u16* xb  = w;            // dead after Q projection
  u16* O   = w; w += nx;   // attn half-1 partial, then final O (in-place merge)
  u16* yb  = w; w += ny;   // dead after V gemm -> attn half-0 f32 partial
  u16* Wqb = w; w += nw;   // dead after Q gemm -> attn m/l stats
  u16* Wkb = w; w += nw;
  u16* Wvb = w; w += nw;
  u16* Wob = w; w += nw;
  u16* Qm  = w; w += nx;
  u16* Km  = w; w += ny;
  u16* Vt  = w; w += ny;   // [8][512][4096]

  float* P0f = (float*)yb;           // nx f32 = 33,554,432 B (exact fit in yb)
  float* Mst = (float*)Wqb;          // 2*16384 f32
  float* Lst = Mst + 2 * 16384;      // 2*16384 f32 (total 256KB <= 512KB)

  // one fused fp32->bf16 conversion over the contiguous region
  cvt_all_kernel<<<25600, 256, 0, stream>>>(x, y, Wq, Wk, Wv, Wo, xb);

  // Qm = (x@Wq^T) * 1/sqrt(512)
  const float scal = 0.04419417382415922f;
  gemm_bt<EPI_BF16_SCALE><<<dim3(128, 4, 1), 256, 0, stream>>>(
      xb, Wqb, Qm, 16384, EMBED, EMBED, 0, 0, 0, scal, nullptr, nullptr, nullptr);
  gemm_bt<EPI_BF16><<<dim3(256, 4, 1), 256, 0, stream>>>(
      yb, Wkb, Km, 32768, EMBED, EMBED, 0, 0, 0, 1.f, nullptr, nullptr, nullptr);
  gemm_bt<EPI_BF16_TRANS><<<dim3(256, 4, 1), 256, 0, stream>>>(
      yb, Wvb, nullptr, 32768, EMBED, EMBED, 0, 0, 0, 1.f, nullptr, nullptr, Vt);

  // fused attention, 2-way split-K (y = key half); partials + stats
  attn_kernel<<<dim3(256, 2), 256, 0, stream>>>(Qm, Km, Vt, O, P0f, Mst, Lst);

  // combine halves into final bf16 O (in place over the half-1 partial)
  merge_kernel<<<4096, 256, 0, stream>>>(P0f, O, Mst, Lst);

  // out = x + O @ Wo^T + bo   (fp32 epilogue)
  gemm_bt<EPI_F32_RESID><<<dim3(128, 4, 1), 256, 0, stream>>>(
      O, Wob, out, 16384, EMBED, EMBED, 0, 0, 0, 1.f, x, bo, nullptr);
}